// Round 10
// baseline (3290.845 us; speedup 1.0000x reference)
//
#include <hip/hip_runtime.h>
#include <math.h>

// Problem constants (fixed by setup_inputs)
#define NB 64
#define NC 256
#define NHW 16
#define NE 8192
#define NUMEL 4194304          // 64*256*16*16
#define LOSS_OFF 4194304
#define CNT_OFF  4194305

typedef __bf16 bf16x8 __attribute__((ext_vector_type(8)));
typedef float  f32x4  __attribute__((ext_vector_type(4)));

#define GLOAD_LDS(gptr, lptr) \
  __builtin_amdgcn_global_load_lds( \
      (const __attribute__((address_space(1))) unsigned int*)(gptr), \
      (__attribute__((address_space(3))) unsigned int*)(lptr), 16, 0, 0)

// ---------------- helpers ----------------
__device__ __forceinline__ float cubicw(float t) {
  // torch bicubic, a = -0.75
  t = fabsf(t);
  if (t <= 1.0f) return (1.25f * t - 2.25f) * t * t + 1.0f;
  if (t < 2.0f)  return ((-0.75f * t + 3.75f) * t - 6.0f) * t + 3.0f;
  return 0.0f;
}

__device__ __forceinline__ short f2bf(float x) {
  union { float f; unsigned int u; } v; v.f = x;
  unsigned int r = v.u + 0x7fffu + ((v.u >> 16) & 1u);  // RNE
  return (short)(r >> 16);
}
__device__ __forceinline__ float bf2f(short h) {
  union { float f; unsigned int u; } v;
  v.u = ((unsigned int)(unsigned short)h) << 16;
  return v.f;
}

// ---------------- prep kernels ----------------
// zero loss + counts region of d_out
__global__ void k_zero(float* a, int na) {
  int i = blockIdx.x * 256 + threadIdx.x;
  if (i < na) a[i] = 0.0f;
}

// z (NCHW) -> z_rest NHWC [16384][256]
__global__ void k_tr_in(const float* __restrict__ z, float* __restrict__ zrest) {
  int n = blockIdx.x, c = threadIdx.x;
  int b = n >> 8, hw = n & 255;
  zrest[(size_t)n * 256 + c] = z[((size_t)(b * 256 + c)) * 256 + hw];
}

// embedding [8192][256] -> B2 [8192][768] bf16 rows = [hi, hi, lo]; esq[8192] fp32
__global__ void k_prep_emb2(const float* __restrict__ emb, short* __restrict__ B2,
                            float* __restrict__ esq) {
  int j = blockIdx.x, t = threadIdx.x;
  float v = emb[(size_t)j * 256 + t];
  short hi = f2bf(v);
  short lo = f2bf(v - bf2f(hi));
  B2[(size_t)j * 768 + t]       = hi;
  B2[(size_t)j * 768 + 256 + t] = hi;
  B2[(size_t)j * 768 + 512 + t] = lo;
  __shared__ float red[256];
  red[t] = v * v;
  __syncthreads();
  for (int s = 128; s > 0; s >>= 1) { if (t < s) red[t] += red[t + s]; __syncthreads(); }
  if (t == 0) esq[j] = red[0];
}

// conv_w [si][o][i][kh][kw] -> wB2 [si][tap][o][768] bf16 rows = [hi, hi, lo]
__global__ void k_prep_wb(const float* __restrict__ w, short* __restrict__ wB2) {
  int m = blockIdx.x * 256 + threadIdx.x;
  if (m >= 8 * 9 * 65536) return;
  int i = m & 255, o = (m >> 8) & 255;
  int r = m >> 16;            // si*9 + tap
  int si = r / 9, tap = r % 9;
  float v = w[(((size_t)si * 256 + o) * 256 + i) * 9 + tap];
  short hi = f2bf(v);
  short lo = f2bf(v - bf2f(hi));
  size_t dst = ((size_t)r * 256 + o) * 768;
  wB2[dst + i]       = hi;
  wB2[dst + 256 + i] = hi;
  wB2[dst + 512 + i] = lo;
}

// ---------------- per-scale kernels ----------------
// area downsample: z_rest NHWC -> A2 rows [hi, lo, hi]
__global__ void k_down_a2(const float* __restrict__ zrest, short* __restrict__ A2, int pn) {
  int pq = blockIdx.x, b = blockIdx.y, c = threadIdx.x;
  int p = pq / pn, q = pq % pn;
  int sp = (p * 16) / pn, ep = ((p + 1) * 16 + pn - 1) / pn;
  int sq = (q * 16) / pn, eq = ((q + 1) * 16 + pn - 1) / pn;
  float s = 0.0f;
  for (int h = sp; h < ep; h++)
    for (int w = sq; w < eq; w++)
      s += zrest[((size_t)((b * 16 + h) * 16 + w)) * 256 + c];
  float x = s / (float)((ep - sp) * (eq - sq));
  int n = (b * pn + p) * pn + q;
  short hi = f2bf(x);
  short lo = f2bf(x - bf2f(hi));
  A2[(size_t)n * 768 + c]       = hi;
  A2[(size_t)n * 768 + 256 + c] = lo;
  A2[(size_t)n * 768 + 512 + c] = hi;
}

// identity (last scale): z_rest NHWC -> A2
__global__ void k_split_a2(const float* __restrict__ zrest, short* __restrict__ A2) {
  int n = blockIdx.x, c = threadIdx.x;
  float x = zrest[(size_t)n * 256 + c];
  short hi = f2bf(x);
  short lo = f2bf(x - bf2f(hi));
  A2[(size_t)n * 768 + c]       = hi;
  A2[(size_t)n * 768 + 256 + c] = lo;
  A2[(size_t)n * 768 + 512 + c] = hi;
}

// MFMA distance GEMM + fused argmin, R10 structure: BARRIER-FREE K-loop.
// Block = 128 rows x 128 codes, 4 waves as 2x2 (wave-tile 64x64).
// Fragments loaded global->VGPR directly (fully coalesced: lanes lc=rows,
// lq covers each row's 64B line), register double-buffered with prefetch
// distance 1 -> compiler emits partial vmcnt waits (AITER pattern), never
// a full drain. K = 768 walked in 24 steps of 32, ascending (bit-identical
// accumulation to R9). Cross-wave code-half argmin combined via LDS.
__global__ __launch_bounds__(256) void k_dist_mfma(
    const short* __restrict__ A2, const short* __restrict__ B2,
    const float* __restrict__ esq, float* __restrict__ pd, int* __restrict__ pi,
    int N) {
  __shared__ float sbd[2][128];
  __shared__ int   sbi[2][128];
  int t = threadIdx.x, ln = t & 63, wv = t >> 6;
  int wr = wv >> 1, wc = wv & 1;
  int n0 = blockIdx.x * 128, jb0 = blockIdx.y * 128;
  int lc = ln & 15, lq = ln >> 4;

  const short* ap[4];
  const short* bp[4];
#pragma unroll
  for (int rt = 0; rt < 4; rt++)
    ap[rt] = A2 + (size_t)(n0 + wr * 64 + rt * 16 + lc) * 768 + lq * 8;
#pragma unroll
  for (int ct = 0; ct < 4; ct++)
    bp[ct] = B2 + (size_t)(jb0 + wc * 64 + ct * 16 + lc) * 768 + lq * 8;

  f32x4 acc[4][4];
#pragma unroll
  for (int rt = 0; rt < 4; rt++)
#pragma unroll
    for (int ct = 0; ct < 4; ct++) acc[rt][ct] = (f32x4)(0.0f);

  bf16x8 fa0[4], fb0[4], fa1[4], fb1[4];
#pragma unroll
  for (int rt = 0; rt < 4; rt++) fa0[rt] = *(const bf16x8*)(ap[rt]);
#pragma unroll
  for (int ct = 0; ct < 4; ct++) fb0[ct] = *(const bf16x8*)(bp[ct]);

  // 24 K-steps of 32 shorts; unroll-by-2 buffer alternation.
#pragma unroll
  for (int s = 0; s < 24; s += 2) {
    int o1 = (s + 1) * 32, o2 = (s + 2) * 32;
#pragma unroll
    for (int rt = 0; rt < 4; rt++) fa1[rt] = *(const bf16x8*)(ap[rt] + o1);
#pragma unroll
    for (int ct = 0; ct < 4; ct++) fb1[ct] = *(const bf16x8*)(bp[ct] + o1);
#pragma unroll
    for (int rt = 0; rt < 4; rt++)
#pragma unroll
      for (int ct = 0; ct < 4; ct++)
        acc[rt][ct] = __builtin_amdgcn_mfma_f32_16x16x32_bf16(
            fa0[rt], fb0[ct], acc[rt][ct], 0, 0, 0);
    if (s + 2 < 24) {
#pragma unroll
      for (int rt = 0; rt < 4; rt++) fa0[rt] = *(const bf16x8*)(ap[rt] + o2);
#pragma unroll
      for (int ct = 0; ct < 4; ct++) fb0[ct] = *(const bf16x8*)(bp[ct] + o2);
    }
#pragma unroll
    for (int rt = 0; rt < 4; rt++)
#pragma unroll
      for (int ct = 0; ct < 4; ct++)
        acc[rt][ct] = __builtin_amdgcn_mfma_f32_16x16x32_bf16(
            fa1[rt], fb1[ct], acc[rt][ct], 0, 0, 0);
  }

  // epilogue: dist = esq[j] - 2*dot; per-row argmin over this block's codes.
  float best[4][4]; int bidx[4][4];
#pragma unroll
  for (int rt = 0; rt < 4; rt++)
#pragma unroll
    for (int r = 0; r < 4; r++) { best[rt][r] = 3.4e38f; bidx[rt][r] = 0; }
#pragma unroll
  for (int rt = 0; rt < 4; rt++)
#pragma unroll
    for (int ct = 0; ct < 4; ct++) {
      int j = jb0 + wc * 64 + ct * 16 + lc;
      float es = esq[j];
#pragma unroll
      for (int r = 0; r < 4; r++) {
        float d = es - 2.0f * acc[rt][ct][r];
        if (d < best[rt][r]) { best[rt][r] = d; bidx[rt][r] = j; }
      }
    }

#pragma unroll
  for (int rt = 0; rt < 4; rt++) {
#pragma unroll
    for (int r = 0; r < 4; r++) {
      float bd = best[rt][r]; int bi = bidx[rt][r];
#pragma unroll
      for (int off = 1; off < 16; off <<= 1) {
        float od = __shfl_xor(bd, off, 64);
        int   oi = __shfl_xor(bi, off, 64);
        if (od < bd || (od == bd && oi < bi)) { bd = od; bi = oi; }
      }
      if (lc == 0) {
        int rloc = wr * 64 + rt * 16 + lq * 4 + r;
        sbd[wc][rloc] = bd;
        sbi[wc][rloc] = bi;
      }
    }
  }
  __syncthreads();
  // combine the two code-halves (wc=0 holds lower j: strict '<' keeps ties low)
  if (t < 128) {
    float b0 = sbd[0][t]; int i0 = sbi[0][t];
    float b1 = sbd[1][t]; int i1 = sbi[1][t];
    if (b1 < b0 || (b1 == b0 && i1 < i0)) { b0 = b1; i0 = i1; }
    int n = n0 + t;
    if (n < N) {
      pd[(size_t)n * 64 + blockIdx.y] = b0;
      pi[(size_t)n * 64 + blockIdx.y] = i0;
    }
  }
}

// reduce per-row partials over 64 code tiles -> idx, counts
__global__ void k_red(const float* __restrict__ pd, const int* __restrict__ pi,
                      int* __restrict__ idxb, float* __restrict__ counts, int N, int nct) {
  int n = blockIdx.x * 256 + threadIdx.x;
  if (n >= N) return;
  float bd = pd[(size_t)n * nct]; int bi = pi[(size_t)n * nct];
  for (int jt = 1; jt < nct; jt++) {
    float d = pd[(size_t)n * nct + jt]; int ii = pi[(size_t)n * nct + jt];
    if (d < bd || (d == bd && ii < bi)) { bd = d; bi = ii; }
  }
  idxb[n] = bi;
  atomicAdd(counts + bi, 1.0f);
}

// gather + bicubic upsample -> zu fp32 NHWC and zu2 compensated [hi,lo,hi]
__global__ void k_up(const float* __restrict__ emb, const int* __restrict__ idxb,
                     float* __restrict__ zu, short* __restrict__ zu2, int pn, int last) {
  int n = blockIdx.x, c = threadIdx.x;
  float acc;
  if (last) {
    acc = emb[(size_t)idxb[n] * 256 + c];
  } else {
    int b = n >> 8, hw = n & 255, h = hw >> 4, w = hw & 15;
    float scale = pn / 16.0f;
    float xh = (h + 0.5f) * scale - 0.5f; int fh = (int)floorf(xh);
    float xw = (w + 0.5f) * scale - 0.5f; int fw = (int)floorf(xw);
    int ph[4], pw[4]; float wh[4], wwt[4];
#pragma unroll
    for (int k = 0; k < 4; k++) {
      wh[k] = cubicw(xh - (float)(fh + k - 1));
      int pp = fh + k - 1; ph[k] = min(max(pp, 0), pn - 1);
      wwt[k] = cubicw(xw - (float)(fw + k - 1));
      pp = fw + k - 1; pw[k] = min(max(pp, 0), pn - 1);
    }
    acc = 0.0f;
#pragma unroll
    for (int kh = 0; kh < 4; kh++)
#pragma unroll
      for (int kw = 0; kw < 4; kw++) {
        int row = idxb[(n >> 8) * pn * pn + ph[kh] * pn + pw[kw]];
        acc += wh[kh] * wwt[kw] * emb[(size_t)row * 256 + c];
      }
  }
  zu[(size_t)n * 256 + c] = acc;
  short hi = f2bf(acc);
  short lo = f2bf(acc - bf2f(hi));
  zu2[(size_t)n * 768 + c]       = hi;
  zu2[(size_t)n * 768 + 256 + c] = lo;
  zu2[(size_t)n * 768 + 512 + c] = hi;
}

// 3x3 SAME conv as compensated-bf16 MFMA GEMM (K = 9 taps x 768) + fused
// bias + residual update + loss. Block: 64 px x 128 o, 4 waves, wave wv
// covers o-sub [wv*32, wv*32+32). Bs via global_load_lds + XOR swizzle;
// As manual (border zeroing) with LDA=72 pad. (unchanged from R7)
#define LDA 72
__global__ __launch_bounds__(256) void k_conv_mfma(
    const short* __restrict__ zu2, const short* __restrict__ wB2,
    const float* __restrict__ cb, const float* __restrict__ zu,
    float* __restrict__ zrest, float* __restrict__ out_loss, int si) {
  __shared__ short As[64 * LDA];
  __shared__ short Bs[128 * 64];
  __shared__ float red[256];
  int t = threadIdx.x, ln = t & 63, wv = t >> 6;
  int lc = ln & 15, lq = ln >> 4;
  int b = blockIdx.x >> 2, h0 = (blockIdx.x & 3) * 4;
  int o0 = blockIdx.y * 128;

  f32x4 acc[4][2];
#pragma unroll
  for (int rt = 0; rt < 4; rt++)
#pragma unroll
    for (int ct = 0; ct < 2; ct++) acc[rt][ct] = (f32x4)(0.0f);

  for (int kh = 0; kh < 3; kh++) {
    for (int kw = 0; kw < 3; kw++) {
      int tap = kh * 3 + kw;
      const short* bbase = wB2 + (((size_t)si * 9 + tap) * 256 + o0) * 768;
      const short* asrc[2]; bool aok[2]; int adst[2];
#pragma unroll
      for (int i = 0; i < 2; i++) {
        int G = i * 256 + t, row = G >> 3, cc = G & 7;
        int hs = h0 + (row >> 4) + kh - 1, ws = (row & 15) + kw - 1;
        aok[i] = (hs >= 0 && hs < 16 && ws >= 0 && ws < 16);
        int nsrc = aok[i] ? (b * 256 + hs * 16 + ws) : 0;
        asrc[i] = zu2 + (size_t)nsrc * 768 + cc * 8;
        adst[i] = row * LDA + cc * 8;
      }
      for (int kc = 0; kc < 12; kc++) {
#pragma unroll
        for (int i = 0; i < 2; i++) {
          uint4 v = make_uint4(0u, 0u, 0u, 0u);
          if (aok[i]) v = *(const uint4*)(asrc[i] + kc * 64);
          *(uint4*)(As + adst[i]) = v;
        }
#pragma unroll
        for (int i = 0; i < 4; i++) {
          int Lb = i * 256 + wv * 64;
          int L = Lb + ln;
          int row = L >> 3, cc = L & 7;
          int gc = cc ^ (row & 7);
          GLOAD_LDS(bbase + (size_t)row * 768 + kc * 64 + gc * 8, Bs + Lb * 8);
        }
        __syncthreads();
#pragma unroll
        for (int ks = 0; ks < 2; ks++) {
          bf16x8 fa[4], fb[2];
#pragma unroll
          for (int rt = 0; rt < 4; rt++)
            fa[rt] = *(const bf16x8*)(As + (rt * 16 + lc) * LDA + (ks * 4 + lq) * 8);
#pragma unroll
          for (int ct = 0; ct < 2; ct++) {
            int row = wv * 32 + ct * 16 + lc;
            int cc = (ks * 4 + lq) ^ (row & 7);
            fb[ct] = *(const bf16x8*)(Bs + row * 64 + cc * 8);
          }
#pragma unroll
          for (int rt = 0; rt < 4; rt++)
#pragma unroll
            for (int ct = 0; ct < 2; ct++)
              acc[rt][ct] = __builtin_amdgcn_mfma_f32_16x16x32_bf16(
                  fa[rt], fb[ct], acc[rt][ct], 0, 0, 0);
        }
        __syncthreads();
      }
    }
  }

  float lsum = 0.0f;
#pragma unroll
  for (int ct = 0; ct < 2; ct++) {
    int o = o0 + wv * 32 + ct * 16 + lc;
    float bias = cb[si * 256 + o];
#pragma unroll
    for (int rt = 0; rt < 4; rt++) {
#pragma unroll
      for (int r = 0; r < 4; r++) {
        int px = rt * 16 + lq * 4 + r;
        int n = b * 256 + (h0 + (px >> 4)) * 16 + (px & 15);
        size_t m = (size_t)n * 256 + o;
        float y = acc[rt][ct][r] + bias;
        float res = 0.5f * (zu[m] + y);
        float nv = zrest[m] - res;
        zrest[m] = nv;
        lsum += nv * nv;
      }
    }
  }
  red[t] = lsum;
  __syncthreads();
  for (int s = 128; s > 0; s >>= 1) { if (t < s) red[t] += red[t + s]; __syncthreads(); }
  if (t == 0) atomicAdd(out_loss, red[0] * (0.25f / (8.0f * 4194304.0f)));
}

// out NCHW = z - z_rest (z_hat_cum)
__global__ void k_out(const float* __restrict__ z, const float* __restrict__ zrest,
                      float* __restrict__ out) {
  int n = blockIdx.x, c = threadIdx.x;
  int b = n >> 8, hw = n & 255;
  size_t m = ((size_t)(b * 256 + c)) * 256 + hw;
  out[m] = z[m] - zrest[(size_t)n * 256 + c];
}

// ---------------- launch ----------------
extern "C" void kernel_launch(void* const* d_in, const int* in_sizes, int n_in,
                              void* d_out, int out_size, void* d_ws, size_t ws_size,
                              hipStream_t stream) {
  const float* z   = (const float*)d_in[0];
  const float* emb = (const float*)d_in[1];
  const float* cw  = (const float*)d_in[2];
  const float* cb  = (const float*)d_in[3];
  float* out = (float*)d_out;
  float* ws  = (float*)d_ws;

  // layout: 27,025,408 floats = 108.1 MB (R1 proved 111.8 MB works)
  float* z_rest = ws;                        // 4,194,304
  float* zu     = ws + 4194304;              // 4,194,304
  float* esq    = ws + 8388608;              // 8,192
  short* A2     = (short*)(ws + 8396800);    // 16384*768 shorts = 6,291,456 floats
  short* zu2    = A2;                        // reuses A2 (free after dist)
  short* B2     = (short*)(ws + 14688256);   // 8192*768 shorts  = 3,145,728 floats
  short* wB2    = (short*)(ws + 17833984);   // 8*9*256*768 shorts = 7,077,888 floats
  float* pd     = ws + 24911872;             // 16384*64 = 1,048,576
  int*   pi     = (int*)(ws + 25960448);     // 1,048,576
  int*   idxb   = (int*)(ws + 27009024);     // 16,384

  const int pns[8] = {1, 2, 3, 4, 6, 8, 12, 16};

  k_zero<<<33, 256, 0, stream>>>(out + LOSS_OFF, 1 + NE);
  k_tr_in<<<16384, 256, 0, stream>>>(z, z_rest);
  k_prep_emb2<<<8192, 256, 0, stream>>>(emb, B2, esq);
  k_prep_wb<<<18432, 256, 0, stream>>>(cw, wB2);

  for (int si = 0; si < 8; si++) {
    int pn = pns[si];
    int N = 64 * pn * pn;
    if (si < 7)
      k_down_a2<<<dim3(pn * pn, 64), 256, 0, stream>>>(z_rest, A2, pn);
    else
      k_split_a2<<<16384, 256, 0, stream>>>(z_rest, A2);
    int rb = (N + 127) / 128;
    k_dist_mfma<<<dim3(rb, 64), 256, 0, stream>>>(A2, B2, esq, pd, pi, N);
    k_red<<<(N + 255) / 256, 256, 0, stream>>>(pd, pi, idxb, out + CNT_OFF, N, 64);
    k_up<<<16384, 256, 0, stream>>>(emb, idxb, zu, zu2, pn, si == 7 ? 1 : 0);
    k_conv_mfma<<<dim3(256, 2), 256, 0, stream>>>(zu2, wB2, cb, zu, z_rest,
                                                  out + LOSS_OFF, si);
  }
  k_out<<<16384, 256, 0, stream>>>(z, z_rest, out);
}